// Round 12
// baseline (851.210 us; speedup 1.0000x reference)
//
#include <hip/hip_runtime.h>
#include <math.h>

// ---------------------------------------------------------------------------
// DsDTW pipeline (round 24):
//  - dtw restructured: 8 waves x 128 rows, TWO rows per lane (r0=2l, r1=2l+1).
//    Cell r1 depends only on in-lane values (up1 = own n0(t-1), diag1 = own
//    n0(t-2)) -> the two softmins per step are ILP-independent; ONE DPP per
//    step; D loads / R stores are packed dwords (2 rows). Epochs 79 -> 71
//    (lag 4W, 36 chunks/wave). EDGE chunks use predicated d16_hi half-stores
//    (preserves the single-valid-write-per-slot ring invariant).
//    Numerics identical (same f32 chain, same bf16 truncation points).
//  - Idle waves 8..15 of dtw blocks just run the 71-barrier loop.
//  - attn_k (row-pair staging, swizzle), mm_k, mgemm, conv: R11 unchanged.
// B=32, C_IN=12, T=4095, D=128, L=1024, GAMMA=5.
// ---------------------------------------------------------------------------

#define L_SEQ 1024
#define DM 128
#define INF_F __builtin_inff()

// log2(e)/gamma and 2*log2(e)/gamma
#define K_SCALE 0.28853900817779268f
#define K2_SCALE 0.57707801635558536f

typedef short s16x8 __attribute__((ext_vector_type(8)));
typedef float f32x4 __attribute__((ext_vector_type(4)));
typedef unsigned short u16;

__device__ __forceinline__ float b2f(u16 u) {
    return __uint_as_float(((unsigned)u) << 16);
}
__device__ __forceinline__ u16 f2b(float f) {  // RNE
    unsigned u = __float_as_uint(f);
    return (u16)((u + 0x7FFFu + ((u >> 16) & 1u)) >> 16);
}

__device__ __forceinline__ float fexp2(float x) {
    float r;
    asm("v_exp_f32 %0, %1" : "=v"(r) : "v"(x));
    return r;
}
__device__ __forceinline__ float flog2(float x) {
    float r;
    asm("v_log_f32 %0, %1" : "=v"(r) : "v"(x));
    return r;
}

__device__ __forceinline__ float shup1(float x) {
#if __has_builtin(__builtin_amdgcn_mov_dpp)
    return __int_as_float(
        __builtin_amdgcn_mov_dpp(__float_as_int(x), 0x138, 0xF, 0xF, true));
#else
    return __shfl_up(x, 1);
#endif
}

// Sb bank swizzle: XOR u16-col bits 3..5 with row bits 0..2 (keeps 8-u16
// blocks contiguous -> s16x8 reads stay 16B-aligned).
__device__ __forceinline__ int swz(int row, int col) {
    return col ^ ((row & 7) << 3);
}

// ---------------- conv + pool + relu + mask + row norms --------------------
__global__ __launch_bounds__(128) void conv_k(
    const float* __restrict__ x, const float* __restrict__ w,
    const float* __restrict__ cb, const float* __restrict__ mask,
    float* __restrict__ h, u16* __restrict__ hbf, float* __restrict__ norms)
{
    int b = blockIdx.x;
    int l0 = blockIdx.y * 8;
    int d = threadIdx.x;
    __shared__ float xs[12][36];
    __shared__ float red2[8][2];
    for (int v = d; v < 12 * 35; v += 128) {
        int c = v / 35, off = v % 35;
        int gi = 4 * l0 - 2 + off;
        xs[c][off] = (gi >= 0 && gi < 4095) ? x[((long)b * 12 + c) * 4095 + gi] : 0.f;
    }
    __syncthreads();
    float s[8];
#pragma unroll
    for (int l = 0; l < 8; ++l) s[l] = 0.f;
    for (int c = 0; c < 12; ++c) {
        const float* wp = w + (d * 12 + c) * 4;
        float w0 = wp[0], w1 = wp[1], w2 = wp[2], w3 = wp[3];
        float e0 = w0, e1 = w0 + w1, e2 = w0 + w1 + w2, e3 = w0 + w1 + w2 + w3;
        float e4 = w1 + w2 + w3, e5 = w2 + w3, e6 = w3;
#pragma unroll
        for (int l = 0; l < 8; ++l) {
            int ba = 4 * l;
            s[l] += xs[c][ba] * e0 + xs[c][ba + 1] * e1 + xs[c][ba + 2] * e2 +
                    xs[c][ba + 3] * e3 + xs[c][ba + 4] * e4 + xs[c][ba + 5] * e5 +
                    xs[c][ba + 6] * e6;
        }
    }
    float cbd = cb[d];
#pragma unroll
    for (int l = 0; l < 8; ++l) {
        int gl = l0 + l;
        float val = fmaxf(cbd + 0.25f * s[l], 0.f) * mask[b * L_SEQ + gl];
        long idx = ((long)(b * L_SEQ + gl)) * DM + d;
        h[idx] = val;
        hbf[idx] = f2b(val);
        float vsq = val * val;
#pragma unroll
        for (int m = 1; m < 64; m <<= 1) vsq += __shfl_xor(vsq, m);
        if ((d & 63) == 0) red2[l][d >> 6] = vsq;
    }
    __syncthreads();
    if (d < 8)
        norms[(long)b * L_SEQ + l0 + d] = (red2[d][0] + red2[d][1]) * K_SCALE;
}

// ----------------------- weight fp32 -> bf16 convert -----------------------
__global__ __launch_bounds__(256) void wcvt_k(
    const float* __restrict__ w1, const float* __restrict__ w2,
    const float* __restrict__ w3, const float* __restrict__ w4,
    u16* __restrict__ o)
{
    int i = blockIdx.x * 256 + threadIdx.x;   // grid 200 -> 51200
    float v;
    if (i < 16384) v = w1[i];
    else if (i < 32768) v = w2[i - 16384];
    else if (i < 49152) v = w3[i - 32768];
    else v = w4[i - 49152];
    o[i] = f2b(v);
}

// --------------------------- MFMA D2 GEMM ----------------------------------
__global__ __launch_bounds__(256) void mgemm_k(
    const u16* __restrict__ A0, const u16* __restrict__ B0, void* __restrict__ C0,
    const float* __restrict__ e0)
{
    const int z = blockIdx.z;
    const u16* A = A0;
    const u16* B = B0 + (long)z * 131072L;
    const int tid = threadIdx.x, wv = tid >> 6, lane = tid & 63;
    const int m0 = blockIdx.x * 64, n0 = blockIdx.y * 64;
    const int co = lane & 15;
    const int q8 = (lane >> 4) << 3;
    const int mrow = m0 + 16 * wv + co;

    f32x4 acc[4];
#pragma unroll
    for (int tn = 0; tn < 4; ++tn) acc[tn] = 0.f;

    for (int kk = 0; kk < 4; ++kk) {
        const int k0 = kk * 32 + q8;
        const s16x8 a = *reinterpret_cast<const s16x8*>(A + (long)mrow * 128 + k0);
#pragma unroll
        for (int tn = 0; tn < 4; ++tn) {
            const s16x8 b = *reinterpret_cast<const s16x8*>(
                B + (long)(n0 + 16 * tn + co) * 128 + k0);
            acc[tn] = __builtin_amdgcn_mfma_f32_16x16x32_bf16(a, b, acc[tn], 0, 0, 0);
        }
    }

    const int li0 = 16 * wv + ((lane >> 4) << 2);

    __shared__ float Cs[64][66];
    float ni[4];
#pragma unroll
    for (int r = 0; r < 4; ++r) ni[r] = e0[m0 + li0 + r];
#pragma unroll
    for (int tn = 0; tn < 4; ++tn) {
        float nj = e0[(long)z * L_SEQ + n0 + 16 * tn + co];
#pragma unroll
        for (int r = 0; r < 4; ++r)
            Cs[li0 + r][16 * tn + co] = ni[r] + nj - K2_SCALE * acc[tn][r];
    }
    __syncthreads();
    u16* Cu = (u16*)C0 + (long)z * 1048576L;
    for (int q = 0; q < 32; ++q) {
        int dd = wv * 32 + q;
        if (dd < 127) {
            int d = m0 + n0 + dd;
            int ilo = max(m0, d - n0 - 63);
            int ihi = min(m0 + 63, d - n0);
            int i = ilo + lane;
            if (i <= ihi)
                Cu[(long)(((d & 1023) << 10) + i)] = f2b(Cs[i - m0][d - n0 - i]);
        }
    }
}

// ---- fused attention: R-stage + QK + softmax + AV + transformer tail ------
__global__ __launch_bounds__(1024) void attn_k(
    const u16* __restrict__ qb, const u16* __restrict__ kb,
    const u16* __restrict__ vt, const u16* __restrict__ Rm,
    const float* __restrict__ mnmx8, const float* __restrict__ mask,
    float* __restrict__ rsum, const float* __restrict__ h,
    const u16* __restrict__ wb, const float* __restrict__ b_out,
    const float* __restrict__ ln1_g, const float* __restrict__ ln1_b,
    const float* __restrict__ b_ff1, const float* __restrict__ b_ff2,
    const float* __restrict__ ln2_g, const float* __restrict__ ln2_b,
    float* __restrict__ out)
{
    __shared__ __align__(16) char smem[65536];
    u16 (*Sb)[1024] = reinterpret_cast<u16 (*)[1024]>(smem);

    const int z = blockIdx.y;
    const int m0 = blockIdx.x * 32;
    const int tid = threadIdx.x, w = tid >> 6, lane = tid & 63;
    const int co = lane & 15;
    const int q8 = (lane >> 4) << 3;
    const int r0 = (lane >> 4) << 2;

    const u16* woutb = wb;
    const u16* wff1b = wb + 16384;
    const u16* wff2b = wb + 32768;
    const u16* wlinb = wb + 49152;

    // ---- phase 1: stage R diagonals (row-pair ushort2, coalesced) -------
    {
        const u16* Rz = Rm + (long)z * 1048576L;
        const int base = m0 + 64 * w;          // diagonal t base for tile
        const int tq = lane >> 4;              // 0..3 (t offset)
        const int rp = lane & 15;              // row-pair index
        const int i0 = 2 * rp, i1 = i0 + 1;
#pragma unroll
        for (int d0 = 0; d0 < 96; d0 += 4) {
            const int t = base + d0 + tq;
            const ushort2 v = *reinterpret_cast<const ushort2*>(
                Rz + (long)(((t & 1023) << 10) + m0 + i0));
            const int c0 = d0 + tq - i0;       // col within tile for row i0
            const int c1 = c0 - 1;             // row i1
            if ((unsigned)c0 < 64u) Sb[i0][swz(i0, 64 * w + c0)] = v.x;
            if ((unsigned)c1 < 64u) Sb[i1][swz(i1, 64 * w + c1)] = v.y;
        }
    }
    // wave-local ds write->read ordering is guaranteed per-wave

    // ---- phase 2: QK scores for the tile (wave-local) -------------------
    {
        const u16* Az = qb + (long)z * 131072L;
        const u16* Bz = kb + (long)z * 131072L;
        float mn = INF_F, mx = -INF_F;
#pragma unroll
        for (int i = 0; i < 8; ++i) {
            mn = fminf(mn, mnmx8[(z * 8 + i) * 2 + 0]);
            mx = fmaxf(mx, mnmx8[(z * 8 + i) * 2 + 1]);
        }
        const float inv = 1.f / (mx - mn);
        f32x4 acc[2][4];
#pragma unroll
        for (int rg = 0; rg < 2; ++rg)
#pragma unroll
            for (int tn = 0; tn < 4; ++tn) acc[rg][tn] = 0.f;
#pragma unroll
        for (int kk = 0; kk < 4; ++kk) {
            const int k0 = kk * 32 + q8;
            const s16x8 a0 = *reinterpret_cast<const s16x8*>(
                Az + (long)(m0 + co) * 128 + k0);
            const s16x8 a1 = *reinterpret_cast<const s16x8*>(
                Az + (long)(m0 + 16 + co) * 128 + k0);
#pragma unroll
            for (int tn = 0; tn < 4; ++tn) {
                const s16x8 b = *reinterpret_cast<const s16x8*>(
                    Bz + (long)(64 * w + 16 * tn + co) * 128 + k0);
                acc[0][tn] = __builtin_amdgcn_mfma_f32_16x16x32_bf16(a0, b, acc[0][tn], 0, 0, 0);
                acc[1][tn] = __builtin_amdgcn_mfma_f32_16x16x32_bf16(a1, b, acc[1][tn], 0, 0, 0);
            }
        }
#pragma unroll
        for (int tn = 0; tn < 4; ++tn) {
            const int j = 64 * w + 16 * tn + co;
            const float kp = (mask[(long)z * L_SEQ + j] > 0.f) ? 0.f : -INF_F;
#pragma unroll
            for (int rg = 0; rg < 2; ++rg)
#pragma unroll
                for (int r = 0; r < 4; ++r) {
                    const int rowL = 16 * rg + r0 + r;
                    const int cs = swz(rowL, j);
                    float val = acc[rg][tn][r] * 0.08838834764831845f +
                                (b2f(Sb[rowL][cs]) - mn) * inv + 1.f + kp;
                    Sb[rowL][cs] = f2b(val);
                }
        }
    }
    __syncthreads();

    // ---- phase 3: row softmax in LDS (2 rows/wave, conflict-free u16x2) -
    {
#pragma unroll
        for (int rr = 0; rr < 2; ++rr) {
            const int row = 2 * w + rr;
            const int sw = (row & 7) << 3;
            u16* prow = Sb[row];
            float f[16];
#pragma unroll
            for (int q = 0; q < 8; ++q) {
                ushort2 v = *reinterpret_cast<ushort2*>(
                    &prow[(lane * 2 + 128 * q) ^ sw]);
                f[2 * q + 0] = b2f(v.x);
                f[2 * q + 1] = b2f(v.y);
            }
            float m = f[0];
#pragma unroll
            for (int i = 1; i < 16; ++i) m = fmaxf(m, f[i]);
#pragma unroll
            for (int d2 = 1; d2 < 64; d2 <<= 1) m = fmaxf(m, __shfl_xor(m, d2));
            float s = 0.f;
#pragma unroll
            for (int i = 0; i < 16; ++i) {
                f[i] = __expf(f[i] - m);
                s += f[i];
            }
#pragma unroll
            for (int q = 0; q < 8; ++q) {
                ushort2 pv;
                pv.x = f2b(f[2 * q + 0]);
                pv.y = f2b(f[2 * q + 1]);
                *reinterpret_cast<ushort2*>(
                    &prow[(lane * 2 + 128 * q) ^ sw]) = pv;
            }
#pragma unroll
            for (int d2 = 1; d2 < 64; d2 <<= 1) s += __shfl_xor(s, d2);
            if (lane == 0) rsum[(long)z * L_SEQ + m0 + row] = 1.f / s;
        }
    }
    __syncthreads();

    // ---- phase 4: AV (A-frags from Sb, swizzled) ------------------------
    const int rg = w & 1, ch = w >> 1;      // row-group (16 rows), col-slice
    f32x4 av = 0.f;
    {
        const int arow = 16 * rg + co;
        const u16* Vz = vt + (long)z * 131072L + (long)(16 * ch + co) * 1024;
#pragma unroll 4
        for (int kk = 0; kk < 32; ++kk) {
            const int k0 = kk * 32 + q8;
            const s16x8 a = *reinterpret_cast<const s16x8*>(
                &Sb[arow][swz(arow, k0)]);
            const s16x8 b = *reinterpret_cast<const s16x8*>(Vz + k0);
            av = __builtin_amdgcn_mfma_f32_16x16x32_bf16(a, b, av, 0, 0, 0);
        }
    }
    __syncthreads();   // all Sb reads done; Sb dead, Tb/ps may alias

    u16 (*Tb)[136] = reinterpret_cast<u16 (*)[136]>(smem);   // 8704 B
    float* ps_s = reinterpret_cast<float*>(smem + 32768);    // [32][8]
    float* ps_q = reinterpret_cast<float*>(smem + 33792);    // [32][8]
    const int gj = 16 * ch + co;

    {
#pragma unroll
        for (int r = 0; r < 4; ++r) {
            const int rowL = 16 * rg + r0 + r;
            const float rsv = rsum[(long)z * L_SEQ + m0 + rowL];
            Tb[rowL][gj] = f2b(av[r] * rsv);
        }
    }
    __syncthreads();

    // ---- phase 5: wout(+h) -> ln1 -> ff1 -> ff2(+res) -> ln2 -> lin -----
    auto gemm32 = [&](const u16* __restrict__ Bw) -> f32x4 {
        f32x4 a4 = 0.f;
#pragma unroll
        for (int kk = 0; kk < 4; ++kk) {
            const int k0 = kk * 32 + q8;
            const s16x8 a = *reinterpret_cast<const s16x8*>(&Tb[16 * rg + co][k0]);
            const s16x8 b = *reinterpret_cast<const s16x8*>(
                Bw + (long)(16 * ch + co) * 128 + k0);
            a4 = __builtin_amdgcn_mfma_f32_16x16x32_bf16(a, b, a4, 0, 0, 0);
        }
        return a4;
    };

    float v2r[4];   // post-ln1 (ff2 residual)
    // WOUT + h residual + LN1
    {
        f32x4 vv = gemm32(woutb);
        const float bo = b_out[gj];
        const float* hz = h + ((long)z * L_SEQ + m0) * 128;
        float sr[4], qr[4];
#pragma unroll
        for (int r = 0; r < 4; ++r) {
            const int rowL = 16 * rg + r0 + r;
            float v1 = vv[r] + bo + hz[(long)rowL * 128 + gj];
            vv[r] = v1;
            sr[r] = v1;
            qr[r] = v1 * v1;
        }
#pragma unroll
        for (int m = 1; m < 16; m <<= 1)
#pragma unroll
            for (int r = 0; r < 4; ++r) {
                sr[r] += __shfl_xor(sr[r], m);
                qr[r] += __shfl_xor(qr[r], m);
            }
        if (co == 0) {
#pragma unroll
            for (int r = 0; r < 4; ++r) {
                const int rowL = 16 * rg + r0 + r;
                ps_s[rowL * 8 + ch] = sr[r];
                ps_q[rowL * 8 + ch] = qr[r];
            }
        }
        __syncthreads();   // ps visible; all Tb reads (wout) done
        const float g1 = ln1_g[gj], bb1 = ln1_b[gj];
#pragma unroll
        for (int r = 0; r < 4; ++r) {
            const int rowL = 16 * rg + r0 + r;
            float st = 0.f, qt = 0.f;
#pragma unroll
            for (int c = 0; c < 8; ++c) {
                st += ps_s[rowL * 8 + c];
                qt += ps_q[rowL * 8 + c];
            }
            const float mean = st * (1.f / 128.f);
            const float var = qt * (1.f / 128.f) - mean * mean;
            const float rstd = rsqrtf(var + 1e-5f);
            const float v = (vv[r] - mean) * rstd * g1 + bb1;
            v2r[r] = v;
            Tb[rowL][gj] = f2b(v);
        }
    }
    __syncthreads();

    // FF1 + relu
    {
        f32x4 f1 = gemm32(wff1b);
        __syncthreads();   // all Tb reads done
        const float bf = b_ff1[gj];
#pragma unroll
        for (int r = 0; r < 4; ++r)
            Tb[16 * rg + r0 + r][gj] = f2b(fmaxf(f1[r] + bf, 0.f));
    }
    __syncthreads();

    // FF2 + residual + LN2
    {
        f32x4 f2 = gemm32(wff2b);
        const float bf = b_ff2[gj];
        float sr[4], qr[4];
#pragma unroll
        for (int r = 0; r < 4; ++r) {
            float v3 = f2[r] + bf + v2r[r];
            f2[r] = v3;
            sr[r] = v3;
            qr[r] = v3 * v3;
        }
#pragma unroll
        for (int m = 1; m < 16; m <<= 1)
#pragma unroll
            for (int r = 0; r < 4; ++r) {
                sr[r] += __shfl_xor(sr[r], m);
                qr[r] += __shfl_xor(qr[r], m);
            }
        if (co == 0) {
#pragma unroll
            for (int r = 0; r < 4; ++r) {
                const int rowL = 16 * rg + r0 + r;
                ps_s[rowL * 8 + ch] = sr[r];
                ps_q[rowL * 8 + ch] = qr[r];
            }
        }
        __syncthreads();   // ps visible; all Tb reads (ff2) done
        const float g2 = ln2_g[gj], bb2 = ln2_b[gj];
#pragma unroll
        for (int r = 0; r < 4; ++r) {
            const int rowL = 16 * rg + r0 + r;
            float st = 0.f, qt = 0.f;
#pragma unroll
            for (int c = 0; c < 8; ++c) {
                st += ps_s[rowL * 8 + c];
                qt += ps_q[rowL * 8 + c];
            }
            const float mean = st * (1.f / 128.f);
            const float var = qt * (1.f / 128.f) - mean * mean;
            const float rstd = rsqrtf(var + 1e-5f);
            Tb[rowL][gj] = f2b((f2[r] - mean) * rstd * g2 + bb2);
        }
    }
    __syncthreads();

    // LIN (128 -> 16) * mask  (waves with ch==0 only)
    if (ch == 0) {
        f32x4 a1 = 0.f;
#pragma unroll
        for (int kk = 0; kk < 4; ++kk) {
            const int k0 = kk * 32 + q8;
            const s16x8 a = *reinterpret_cast<const s16x8*>(&Tb[16 * rg + co][k0]);
            const s16x8 b = *reinterpret_cast<const s16x8*>(
                wlinb + (long)co * 128 + k0);
            a1 = __builtin_amdgcn_mfma_f32_16x16x32_bf16(a, b, a1, 0, 0, 0);
        }
#pragma unroll
        for (int r = 0; r < 4; ++r) {
            const long grow = (long)z * L_SEQ + m0 + 16 * rg + r0 + r;
            out[grow * 16 + co] = a1[r] * mask[grow];
        }
    }
}

// ------------------------------- soft-DTW ----------------------------------
// base-2 scaled domain: n = d + mn - log2(1 + 2^(mn-md) + 2^(mn-mx))
__device__ __forceinline__ float softmin3(float d, float rl, float ru, float rul)
{
    float mn = fminf(rul, fminf(ru, rl));
    float md = __builtin_amdgcn_fmed3f(rul, ru, rl);
    float mx = fmaxf(rul, fmaxf(ru, rl));
    float s = 1.f + fexp2(mn - md) + fexp2(mn - mx);
    return d + mn - flog2(s);
}

#define DLOAD32(i, P, OFFS)                                              \
    asm volatile("global_load_dword %0, %1, off offset:" OFFS            \
                 : "=v"(dn[i]) : "v"(P))
#define SSTORE32(P, OFFS, V)                                             \
    asm volatile("global_store_dword %0, %1, off offset:" OFFS           \
                 :: "v"(P), "v"(V))
#define SSTORE16HI(P, OFFS, V)                                           \
    asm volatile("global_store_short_d16_hi %0, %1, off offset:" OFFS    \
                 :: "v"(P), "v"(V))

// 2 rows per lane (r0=2l even, r1=r0+1). Skewed [t&1023][row] layout,
// pointer-bumped dword loads/stores. Cell1 deps are in-lane: up1 = own
// n0(t-1) (cur0), diag1 = own n0(t-2) (c0p). Cell0 deps: up0 = lane l-1's
// n1(t-1) via DPP (sh1) or bb window for lane0; diag0 = previous up0 (u0p).
template <bool EDGE, bool W0>
__device__ __forceinline__ void dtw_chunk2(
    const float* __restrict__ botp, float* __restrict__ botw,
    float* __restrict__ dums, int lane, int rowbase, int r0, int T0,
    float& cur0, float& cur1, float& c0p, float& u0p, float& sh1,
    unsigned (&dnc)[8], unsigned (&dn)[8], float (&bb)[9],
    const u16*& ldp, u16*& stp)
{
    const bool lane0 = (lane == 0);
    const bool lane63 = (lane == 63);
    for (int g = 0; g < 4; ++g) {
        const int tg = T0 + (g << 3);
        const int jg0 = tg - r0;
        // ring-wrap corrections (wave-uniform; only at group boundaries)
        if (((tg + 8) & 1023) == 0) ldp -= 1048576;
        if (tg == 1024) stp -= 1048576;
        // issue next group's 8 packed D loads (steps tg+8 .. tg+15)
        {
            const u16* l2 = ldp + 2048;
            const u16* l4 = ldp + 4096;
            const u16* l6 = ldp + 6144;
            DLOAD32(0, ldp, "0"); DLOAD32(1, ldp, "2048");
            DLOAD32(2, l2, "0");  DLOAD32(3, l2, "2048");
            DLOAD32(4, l4, "0");  DLOAD32(5, l4, "2048");
            DLOAD32(6, l6, "0");  DLOAD32(7, l6, "2048");
        }
        float bn[9];
        if (!W0 && g < 3) {
            const int jn = tg + 7 - rowbase;
            if (EDGE) {
#pragma unroll
                for (int q = 0; q < 9; ++q) bn[q] = botp[(jn + q) & 1023];
            } else {
#pragma unroll
                for (int q = 0; q < 9; ++q) bn[q] = botp[jn + q];
            }
        }
        u16* s2 = stp + 2048;
        u16* s4 = stp + 4096;
        u16* s6 = stp + 6144;
#pragma unroll
        for (int s = 0; s < 8; ++s) {
            const int j0 = jg0 + s;
            const float d0 = __uint_as_float(dnc[s] << 16);
            const float d1 = __uint_as_float(dnc[s] & 0xFFFF0000u);
            float up0 = lane0 ? (W0 ? INF_F : bb[s + 1]) : sh1;
            float dg0;
            if (EDGE) {
                if (W0) dg0 = lane0 ? ((j0 == 0) ? 0.f : INF_F) : u0p;
                else    dg0 = (lane0 && (j0 < 1)) ? INF_F : u0p;
            } else {
                dg0 = (W0 && lane0) ? INF_F : u0p;
            }
            float n0 = softmin3(d0, cur0, up0, dg0);
            float n1 = softmin3(d1, cur1, cur0, c0p);
            u16* sb = (s < 2) ? stp : (s < 4) ? s2 : (s < 6) ? s4 : s6;
            if (EDGE) {
                const bool v0 = ((unsigned)j0 < 1024u);
                const bool v1 = ((unsigned)(j0 - 1) < 1024u);
                n0 = v0 ? n0 : INF_F;
                n1 = v1 ? n1 : INF_F;
                if (v0) {
                    if (s & 1) { SSTORE16HI(sb, "2048", n0); }
                    else       { SSTORE16HI(sb, "0", n0); }
                }
                if (v1) {
                    if (s & 1) { SSTORE16HI(sb, "2050", n1); }
                    else       { SSTORE16HI(sb, "2", n1); }
                }
                float* ba = (lane63 && v1) ? (botw + (j0 - 1)) : (dums + lane);
                *ba = n1;
            } else {
                unsigned pk = (__float_as_uint(n1) & 0xFFFF0000u) |
                              (__float_as_uint(n0) >> 16);
                if (s & 1) { SSTORE32(sb, "2048", pk); }
                else       { SSTORE32(sb, "0", pk); }
                float* ba = lane63 ? (botw + (j0 - 1)) : (dums + lane);
                *ba = n1;
            }
            c0p = cur0;
            cur0 = n0;
            cur1 = n1;
            u0p = up0;
            sh1 = shup1(n1);
        }
        if (EDGE) { asm volatile("s_waitcnt vmcnt(0)"); }
        else      { asm volatile("s_waitcnt vmcnt(8)"); }
        __builtin_amdgcn_sched_barrier(0);
#pragma unroll
        for (int s = 0; s < 8; ++s) dnc[s] = dn[s];
        if (!W0 && g < 3) {
#pragma unroll
            for (int q = 0; q < 9; ++q) bb[q] = bn[q];
        }
        ldp += 8192;
        stp += 8192;
    }
}

// dtw (blocks 0..31: 1/sample, 8 active waves x 2 rows/lane) +
// QKV backfill (blocks 32..799)
__global__ __launch_bounds__(1024, 4) void dtw_qkv_k(
    const u16* __restrict__ Dm, u16* __restrict__ Rm,
    const float* __restrict__ h, const float* __restrict__ w_in,
    const float* __restrict__ b_in, u16* __restrict__ qb, u16* __restrict__ vt)
{
    // unioned LDS: QKV As(16640)+Bs(16640)|Tt(33280) | dtw bot 8x1024 f32
    __shared__ __align__(16) char smem[33280];

    if (blockIdx.x >= 32) {
        // ---- QKV backfill: four 64x64 tiles per 1024-thread block ----
        float (*As)[16][65] = reinterpret_cast<float (*)[16][65]>(smem);
        float (*Bs)[16][65] = reinterpret_cast<float (*)[16][65]>(smem + 16640);
        const int quarter = threadIdx.x >> 8;
        const int tid = threadIdx.x & 255;
        const int t = ((blockIdx.x - 32) << 2) + quarter;   // 0..3071
        const int m0 = (t & 511) << 6;
        const int n0 = (t >> 9) << 6;                       // block-uniform
        int tx = tid & 15, ty = tid >> 4;
        float acc[4][4] = {};
        int am = tid >> 2;
        int ak = (tid & 3) << 2;
        for (int kk = 0; kk < 128; kk += 16) {
            {
                const float4 av = *reinterpret_cast<const float4*>(
                    h + (long)(m0 + am) * 128 + kk + ak);
                As[quarter][ak + 0][am] = av.x;
                As[quarter][ak + 1][am] = av.y;
                As[quarter][ak + 2][am] = av.z;
                As[quarter][ak + 3][am] = av.w;
            }
            {
                const float4 bv = *reinterpret_cast<const float4*>(
                    w_in + (long)(n0 + am) * 128 + kk + ak);
                Bs[quarter][ak + 0][am] = bv.x;
                Bs[quarter][ak + 1][am] = bv.y;
                Bs[quarter][ak + 2][am] = bv.z;
                Bs[quarter][ak + 3][am] = bv.w;
            }
            __syncthreads();
#pragma unroll
            for (int kc = 0; kc < 16; ++kc) {
                float a0 = As[quarter][kc][ty * 4 + 0], a1 = As[quarter][kc][ty * 4 + 1];
                float a2 = As[quarter][kc][ty * 4 + 2], a3 = As[quarter][kc][ty * 4 + 3];
                float b0 = Bs[quarter][kc][tx * 4 + 0], b1 = Bs[quarter][kc][tx * 4 + 1];
                float b2 = Bs[quarter][kc][tx * 4 + 2], b3 = Bs[quarter][kc][tx * 4 + 3];
                acc[0][0] += a0 * b0; acc[0][1] += a0 * b1; acc[0][2] += a0 * b2; acc[0][3] += a0 * b3;
                acc[1][0] += a1 * b0; acc[1][1] += a1 * b1; acc[1][2] += a1 * b2; acc[1][3] += a1 * b3;
                acc[2][0] += a2 * b0; acc[2][1] += a2 * b1; acc[2][2] += a2 * b2; acc[2][3] += a2 * b3;
                acc[3][0] += a3 * b0; acc[3][1] += a3 * b1; acc[3][2] += a3 * b2; acc[3][3] += a3 * b3;
            }
            __syncthreads();
        }
        if (n0 >= 256) {
            // v-tile: write TRANSPOSED into vt [d,1024] via LDS
            u16 (*Tt)[64][65] = reinterpret_cast<u16 (*)[64][65]>(smem);
#pragma unroll
            for (int i = 0; i < 4; ++i)
#pragma unroll
                for (int j = 0; j < 4; ++j)
                    Tt[quarter][tx * 4 + j][ty * 4 + i] =
                        f2b(acc[i][j] + b_in[n0 + tx * 4 + j]);
            __syncthreads();
            const int z = m0 >> 10;
            const int lbase = m0 & 1023;
            const int dbase = n0 - 256;
            u16* dst = vt + (long)z * 131072L;
#pragma unroll
            for (int i = 0; i < 16; ++i) {
                int idx = tid + 256 * i;
                int dj = idx >> 6, li = idx & 63;
                dst[(long)(dbase + dj) * 1024 + lbase + li] = Tt[quarter][dj][li];
            }
            return;
        }
        u16* Cu = qb + ((long)(n0 >> 7)) * 4194304L;
        int cb = (n0 & 127) + tx * 4;
#pragma unroll
        for (int i = 0; i < 4; ++i) {
            int gi = m0 + ty * 4 + i;
            ushort4 sv;
            u16* svp = &sv.x;
#pragma unroll
            for (int j = 0; j < 4; ++j)
                svp[j] = f2b(acc[i][j] + b_in[n0 + tx * 4 + j]);
            *reinterpret_cast<ushort4*>(Cu + (long)gi * 128 + cb) = sv;
        }
        return;
    }

    // ------------------------------- dtw ---------------------------------
    float (*bot)[1024] = reinterpret_cast<float (*)[1024]>(smem);   // 8 rows
    const int tid = threadIdx.x;
    const int lw = tid >> 6;          // 0..15; waves 8..15 idle
    const int lane = tid & 63;

    if (lw >= 8) {
        for (int e = 0; e < 71; ++e) __syncthreads();
        return;
    }

    const int z = blockIdx.x;
    const u16* Dz = Dm + (long)z * 1048576L;
    u16* Rz = Rm + (long)z * 1048576L;
    const int W = lw;                 // 0..7, 128 rows each
    const int rowbase = W << 7;
    const int r0 = rowbase + 2 * lane;   // even row of this lane's pair

    float* botw = (W < 7) ? bot[W] : bot[7];
    const float* botp = (W > 0) ? bot[W - 1] : bot[0];
    float* dums = bot[7];             // dummy row for non-lane63 writes

    float cur0 = INF_F, cur1 = INF_F, c0p = INF_F, u0p = INF_F, sh1 = INF_F;
    unsigned dnc[8], dn[8];
    float bb[9];
    const u16* ldp = Dz;
    u16* stp = Rz;
#pragma unroll
    for (int q = 0; q < 9; ++q) bb[q] = 0.f;
#pragma unroll
    for (int q = 0; q < 8; ++q) { dnc[q] = 0; dn[q] = 0; }

    const int fc = 4 * W;
    for (int e = 0; e < 71; ++e) {
        const int c = e - W;
        const int o = c - fc;
        if (o >= 0 && o <= 35) {
            const int T0 = c << 5;
            if (o == 0) {   // prime pointers + packed D queue (first chunk)
                ldp = Dz + (long)(((T0 + 8) << 10) + r0);
                stp = Rz + (long)((T0 << 10) + r0);
#pragma unroll
                for (int s = 0; s < 8; ++s)
                    dnc[s] = *reinterpret_cast<const unsigned*>(
                        Dz + (long)(((T0 + s) << 10) + r0));
            }
            if (W > 0) {    // bot columns for the chunk's first group
                const int jb = T0 - rowbase - 1;
#pragma unroll
                for (int q = 0; q < 9; ++q) bb[q] = botp[(jb + q) & 1023];
            }
            const bool edge = (o < 4 || o >= 32);
            if (W == 0) {
                if (edge)
                    dtw_chunk2<true, true>(botp, botw, dums, lane, rowbase, r0,
                                           T0, cur0, cur1, c0p, u0p, sh1,
                                           dnc, dn, bb, ldp, stp);
                else
                    dtw_chunk2<false, true>(botp, botw, dums, lane, rowbase, r0,
                                            T0, cur0, cur1, c0p, u0p, sh1,
                                            dnc, dn, bb, ldp, stp);
            } else {
                if (edge)
                    dtw_chunk2<true, false>(botp, botw, dums, lane, rowbase, r0,
                                            T0, cur0, cur1, c0p, u0p, sh1,
                                            dnc, dn, bb, ldp, stp);
                else
                    dtw_chunk2<false, false>(botp, botw, dums, lane, rowbase, r0,
                                             T0, cur0, cur1, c0p, u0p, sh1,
                                             dnc, dn, bb, ldp, stp);
            }
        }
        __syncthreads();
    }
}

// --------- min/max partials over Rmat (8 blocks/sample, full-GPU BW) -------
__global__ __launch_bounds__(1024) void mm_k(const u16* __restrict__ Rm,
                                             float* __restrict__ mnmx8)
{
    const int z = blockIdx.x >> 3, ch = blockIdx.x & 7;
    const uint4* p = reinterpret_cast<const uint4*>(Rm + (long)z * 1048576L) +
                     (long)ch * 16384;
    const int tid = threadIdx.x;
    float mn = INF_F, mx = -INF_F;
#pragma unroll 4
    for (int it = 0; it < 16; ++it) {
        uint4 v = p[it * 1024 + tid];
        unsigned wv[4] = {v.x, v.y, v.z, v.w};
#pragma unroll
        for (int q = 0; q < 4; ++q) {
            float lo = __uint_as_float(wv[q] << 16);
            float hi = __uint_as_float(wv[q] & 0xFFFF0000u);
            mn = fminf(mn, fminf(lo, hi));
            mx = fmaxf(mx, fmaxf(lo, hi));
        }
    }
    __shared__ float rmn[1024];
    __shared__ float rmx[1024];
    rmn[tid] = mn;
    rmx[tid] = mx;
    __syncthreads();
    for (int s2 = 512; s2 > 0; s2 >>= 1) {
        if (tid < s2) {
            rmn[tid] = fminf(rmn[tid], rmn[tid + s2]);
            rmx[tid] = fmaxf(rmx[tid], rmx[tid + s2]);
        }
        __syncthreads();
    }
    if (tid == 0) {
        mnmx8[blockIdx.x * 2 + 0] = rmn[0];
        mnmx8[blockIdx.x * 2 + 1] = rmx[0];
    }
}

// -------------------------------- lengths ----------------------------------
__global__ __launch_bounds__(256) void len_k(const float* __restrict__ mask,
                                             float* __restrict__ out)
{
    int b = blockIdx.x;
    int t = threadIdx.x;
    const float4 v = reinterpret_cast<const float4*>(mask + b * L_SEQ)[t];
    __shared__ float red[256];
    red[t] = v.x + v.y + v.z + v.w;
    __syncthreads();
    for (int s = 128; s > 0; s >>= 1) {
        if (t < s) red[t] += red[t + s];
        __syncthreads();
    }
    if (t == 0) out[b] = red[0];
}

// ------------------------------- launcher ----------------------------------
extern "C" void kernel_launch(void* const* d_in, const int* in_sizes, int n_in,
                              void* d_out, int out_size, void* d_ws, size_t ws_size,
                              hipStream_t stream)
{
    const float* x      = (const float*)d_in[0];
    const float* mask   = (const float*)d_in[1];
    const float* conv_w = (const float*)d_in[2];
    const float* conv_b = (const float*)d_in[3];
    const float* w_in   = (const float*)d_in[4];
    const float* b_in   = (const float*)d_in[5];
    const float* w_out  = (const float*)d_in[6];
    const float* b_out  = (const float*)d_in[7];
    const float* w_ff1  = (const float*)d_in[8];
    const float* b_ff1  = (const float*)d_in[9];
    const float* w_ff2  = (const float*)d_in[10];
    const float* b_ff2  = (const float*)d_in[11];
    const float* ln1_g  = (const float*)d_in[12];
    const float* ln1_b  = (const float*)d_in[13];
    const float* ln2_g  = (const float*)d_in[14];
    const float* ln2_b  = (const float*)d_in[15];
    const float* w_lin  = (const float*)d_in[16];
    float* out = (float*)d_out;

    float* ws    = (float*)d_ws;
    float* h     = ws;
    u16*   qb    = (u16*)(ws + 4194304L);
    u16*   kb    = qb + 4194304L;
    u16*   vt    = qb + 12582912L;
    u16*   hbf   = (u16*)(ws + 25165824L);
    float* mnmx8 = ws + 27297792L;            // 512 floats of partials
    float* norms = ws + 29360128L;
    u16*   woutb = (u16*)norms;               // weights after D2 consumed norms
    float* rsum  = ws + 29425664L;
    u16*   Dmat  = (u16*)(ws + 29458496L);    // D (dtw input; dead after dtw)
    u16*   Rmat  = (u16*)(ws + 46235712L);    // R (dtw output, mm/attn input)

    conv_k<<<dim3(32, 128), 128, 0, stream>>>(x, conv_w, conv_b, mask, h, hbf, norms);
    mgemm_k<<<dim3(16, 16, 32), 256, 0, stream>>>(hbf, hbf, Dmat, norms);
    wcvt_k<<<200, 256, 0, stream>>>(w_out, w_ff1, w_ff2, w_lin, woutb);
    // dtw (32 blocks, 8 waves x 2 rows/lane) + qkv backfill (768 blocks)
    dtw_qkv_k<<<800, 1024, 0, stream>>>(Dmat, Rmat, h, w_in, b_in, qb, vt);
    mm_k<<<256, 1024, 0, stream>>>(Rmat, mnmx8);
    // fused attention: R-stage + QK + softmax + AV + transformer tail
    attn_k<<<dim3(32, 32), 1024, 0, stream>>>(
        qb, kb, vt, Rmat, mnmx8, mask, rsum, h, woutb, b_out,
        ln1_g, ln1_b, b_ff1, b_ff2, ln2_g, ln2_b, out);
    len_k<<<32, 256, 0, stream>>>(mask, out + 32768L * 16);
}

// Round 13
// 766.213 us; speedup vs baseline: 1.1109x; 1.1109x over previous
//
#include <hip/hip_runtime.h>
#include <math.h>

// ---------------------------------------------------------------------------
// DsDTW pipeline (round 25 == round 23 revert):
//  - dtw: R11 structure (1 block/sample, 16 waves x 1 row/lane, skewed
//    [t&1023][row] layout, pointer-bumped asm loads / batched d16_hi stores,
//    counted vmcnt(8), base-2 softmin). R12's 2-rows/lane lengthened the
//    serial chain (2 softmins + DPP per step) at halved wave-parallelism:
//    308 -> 418us. Reverted.
//  - attn_k (row-pair R staging, XOR swizzle), mm_k (256 partials),
//    mgemm, conv: unchanged.
// B=32, C_IN=12, T=4095, D=128, L=1024, GAMMA=5.
// ---------------------------------------------------------------------------

#define L_SEQ 1024
#define DM 128
#define INF_F __builtin_inff()

// log2(e)/gamma and 2*log2(e)/gamma
#define K_SCALE 0.28853900817779268f
#define K2_SCALE 0.57707801635558536f

typedef short s16x8 __attribute__((ext_vector_type(8)));
typedef float f32x4 __attribute__((ext_vector_type(4)));
typedef unsigned short u16;

__device__ __forceinline__ float b2f(u16 u) {
    return __uint_as_float(((unsigned)u) << 16);
}
__device__ __forceinline__ u16 f2b(float f) {  // RNE
    unsigned u = __float_as_uint(f);
    return (u16)((u + 0x7FFFu + ((u >> 16) & 1u)) >> 16);
}

__device__ __forceinline__ float fexp2(float x) {
    float r;
    asm("v_exp_f32 %0, %1" : "=v"(r) : "v"(x));
    return r;
}
__device__ __forceinline__ float flog2(float x) {
    float r;
    asm("v_log_f32 %0, %1" : "=v"(r) : "v"(x));
    return r;
}

__device__ __forceinline__ float shup1(float x) {
#if __has_builtin(__builtin_amdgcn_mov_dpp)
    return __int_as_float(
        __builtin_amdgcn_mov_dpp(__float_as_int(x), 0x138, 0xF, 0xF, true));
#else
    return __shfl_up(x, 1);
#endif
}

// Sb bank swizzle: XOR u16-col bits 3..5 with row bits 0..2 (keeps 8-u16
// blocks contiguous -> s16x8 reads stay 16B-aligned).
__device__ __forceinline__ int swz(int row, int col) {
    return col ^ ((row & 7) << 3);
}

// ---------------- conv + pool + relu + mask + row norms --------------------
__global__ __launch_bounds__(128) void conv_k(
    const float* __restrict__ x, const float* __restrict__ w,
    const float* __restrict__ cb, const float* __restrict__ mask,
    float* __restrict__ h, u16* __restrict__ hbf, float* __restrict__ norms)
{
    int b = blockIdx.x;
    int l0 = blockIdx.y * 8;
    int d = threadIdx.x;
    __shared__ float xs[12][36];
    __shared__ float red2[8][2];
    for (int v = d; v < 12 * 35; v += 128) {
        int c = v / 35, off = v % 35;
        int gi = 4 * l0 - 2 + off;
        xs[c][off] = (gi >= 0 && gi < 4095) ? x[((long)b * 12 + c) * 4095 + gi] : 0.f;
    }
    __syncthreads();
    float s[8];
#pragma unroll
    for (int l = 0; l < 8; ++l) s[l] = 0.f;
    for (int c = 0; c < 12; ++c) {
        const float* wp = w + (d * 12 + c) * 4;
        float w0 = wp[0], w1 = wp[1], w2 = wp[2], w3 = wp[3];
        float e0 = w0, e1 = w0 + w1, e2 = w0 + w1 + w2, e3 = w0 + w1 + w2 + w3;
        float e4 = w1 + w2 + w3, e5 = w2 + w3, e6 = w3;
#pragma unroll
        for (int l = 0; l < 8; ++l) {
            int ba = 4 * l;
            s[l] += xs[c][ba] * e0 + xs[c][ba + 1] * e1 + xs[c][ba + 2] * e2 +
                    xs[c][ba + 3] * e3 + xs[c][ba + 4] * e4 + xs[c][ba + 5] * e5 +
                    xs[c][ba + 6] * e6;
        }
    }
    float cbd = cb[d];
#pragma unroll
    for (int l = 0; l < 8; ++l) {
        int gl = l0 + l;
        float val = fmaxf(cbd + 0.25f * s[l], 0.f) * mask[b * L_SEQ + gl];
        long idx = ((long)(b * L_SEQ + gl)) * DM + d;
        h[idx] = val;
        hbf[idx] = f2b(val);
        float vsq = val * val;
#pragma unroll
        for (int m = 1; m < 64; m <<= 1) vsq += __shfl_xor(vsq, m);
        if ((d & 63) == 0) red2[l][d >> 6] = vsq;
    }
    __syncthreads();
    if (d < 8)
        norms[(long)b * L_SEQ + l0 + d] = (red2[d][0] + red2[d][1]) * K_SCALE;
}

// ----------------------- weight fp32 -> bf16 convert -----------------------
__global__ __launch_bounds__(256) void wcvt_k(
    const float* __restrict__ w1, const float* __restrict__ w2,
    const float* __restrict__ w3, const float* __restrict__ w4,
    u16* __restrict__ o)
{
    int i = blockIdx.x * 256 + threadIdx.x;   // grid 200 -> 51200
    float v;
    if (i < 16384) v = w1[i];
    else if (i < 32768) v = w2[i - 16384];
    else if (i < 49152) v = w3[i - 32768];
    else v = w4[i - 49152];
    o[i] = f2b(v);
}

// --------------------------- MFMA D2 GEMM ----------------------------------
__global__ __launch_bounds__(256) void mgemm_k(
    const u16* __restrict__ A0, const u16* __restrict__ B0, void* __restrict__ C0,
    const float* __restrict__ e0)
{
    const int z = blockIdx.z;
    const u16* A = A0;
    const u16* B = B0 + (long)z * 131072L;
    const int tid = threadIdx.x, wv = tid >> 6, lane = tid & 63;
    const int m0 = blockIdx.x * 64, n0 = blockIdx.y * 64;
    const int co = lane & 15;
    const int q8 = (lane >> 4) << 3;
    const int mrow = m0 + 16 * wv + co;

    f32x4 acc[4];
#pragma unroll
    for (int tn = 0; tn < 4; ++tn) acc[tn] = 0.f;

    for (int kk = 0; kk < 4; ++kk) {
        const int k0 = kk * 32 + q8;
        const s16x8 a = *reinterpret_cast<const s16x8*>(A + (long)mrow * 128 + k0);
#pragma unroll
        for (int tn = 0; tn < 4; ++tn) {
            const s16x8 b = *reinterpret_cast<const s16x8*>(
                B + (long)(n0 + 16 * tn + co) * 128 + k0);
            acc[tn] = __builtin_amdgcn_mfma_f32_16x16x32_bf16(a, b, acc[tn], 0, 0, 0);
        }
    }

    const int li0 = 16 * wv + ((lane >> 4) << 2);

    __shared__ float Cs[64][66];
    float ni[4];
#pragma unroll
    for (int r = 0; r < 4; ++r) ni[r] = e0[m0 + li0 + r];
#pragma unroll
    for (int tn = 0; tn < 4; ++tn) {
        float nj = e0[(long)z * L_SEQ + n0 + 16 * tn + co];
#pragma unroll
        for (int r = 0; r < 4; ++r)
            Cs[li0 + r][16 * tn + co] = ni[r] + nj - K2_SCALE * acc[tn][r];
    }
    __syncthreads();
    u16* Cu = (u16*)C0 + (long)z * 1048576L;
    for (int q = 0; q < 32; ++q) {
        int dd = wv * 32 + q;
        if (dd < 127) {
            int d = m0 + n0 + dd;
            int ilo = max(m0, d - n0 - 63);
            int ihi = min(m0 + 63, d - n0);
            int i = ilo + lane;
            if (i <= ihi)
                Cu[(long)(((d & 1023) << 10) + i)] = f2b(Cs[i - m0][d - n0 - i]);
        }
    }
}

// ---- fused attention: R-stage + QK + softmax + AV + transformer tail ------
__global__ __launch_bounds__(1024) void attn_k(
    const u16* __restrict__ qb, const u16* __restrict__ kb,
    const u16* __restrict__ vt, const u16* __restrict__ Rm,
    const float* __restrict__ mnmx8, const float* __restrict__ mask,
    float* __restrict__ rsum, const float* __restrict__ h,
    const u16* __restrict__ wb, const float* __restrict__ b_out,
    const float* __restrict__ ln1_g, const float* __restrict__ ln1_b,
    const float* __restrict__ b_ff1, const float* __restrict__ b_ff2,
    const float* __restrict__ ln2_g, const float* __restrict__ ln2_b,
    float* __restrict__ out)
{
    __shared__ __align__(16) char smem[65536];
    u16 (*Sb)[1024] = reinterpret_cast<u16 (*)[1024]>(smem);

    const int z = blockIdx.y;
    const int m0 = blockIdx.x * 32;
    const int tid = threadIdx.x, w = tid >> 6, lane = tid & 63;
    const int co = lane & 15;
    const int q8 = (lane >> 4) << 3;
    const int r0 = (lane >> 4) << 2;

    const u16* woutb = wb;
    const u16* wff1b = wb + 16384;
    const u16* wff2b = wb + 32768;
    const u16* wlinb = wb + 49152;

    // ---- phase 1: stage R diagonals (row-pair ushort2, coalesced) -------
    {
        const u16* Rz = Rm + (long)z * 1048576L;
        const int base = m0 + 64 * w;          // diagonal t base for tile
        const int tq = lane >> 4;              // 0..3 (t offset)
        const int rp = lane & 15;              // row-pair index
        const int i0 = 2 * rp, i1 = i0 + 1;
#pragma unroll
        for (int d0 = 0; d0 < 96; d0 += 4) {
            const int t = base + d0 + tq;
            const ushort2 v = *reinterpret_cast<const ushort2*>(
                Rz + (long)(((t & 1023) << 10) + m0 + i0));
            const int c0 = d0 + tq - i0;       // col within tile for row i0
            const int c1 = c0 - 1;             // row i1
            if ((unsigned)c0 < 64u) Sb[i0][swz(i0, 64 * w + c0)] = v.x;
            if ((unsigned)c1 < 64u) Sb[i1][swz(i1, 64 * w + c1)] = v.y;
        }
    }
    // wave-local ds write->read ordering is guaranteed per-wave

    // ---- phase 2: QK scores for the tile (wave-local) -------------------
    {
        const u16* Az = qb + (long)z * 131072L;
        const u16* Bz = kb + (long)z * 131072L;
        float mn = INF_F, mx = -INF_F;
#pragma unroll
        for (int i = 0; i < 8; ++i) {
            mn = fminf(mn, mnmx8[(z * 8 + i) * 2 + 0]);
            mx = fmaxf(mx, mnmx8[(z * 8 + i) * 2 + 1]);
        }
        const float inv = 1.f / (mx - mn);
        f32x4 acc[2][4];
#pragma unroll
        for (int rg = 0; rg < 2; ++rg)
#pragma unroll
            for (int tn = 0; tn < 4; ++tn) acc[rg][tn] = 0.f;
#pragma unroll
        for (int kk = 0; kk < 4; ++kk) {
            const int k0 = kk * 32 + q8;
            const s16x8 a0 = *reinterpret_cast<const s16x8*>(
                Az + (long)(m0 + co) * 128 + k0);
            const s16x8 a1 = *reinterpret_cast<const s16x8*>(
                Az + (long)(m0 + 16 + co) * 128 + k0);
#pragma unroll
            for (int tn = 0; tn < 4; ++tn) {
                const s16x8 b = *reinterpret_cast<const s16x8*>(
                    Bz + (long)(64 * w + 16 * tn + co) * 128 + k0);
                acc[0][tn] = __builtin_amdgcn_mfma_f32_16x16x32_bf16(a0, b, acc[0][tn], 0, 0, 0);
                acc[1][tn] = __builtin_amdgcn_mfma_f32_16x16x32_bf16(a1, b, acc[1][tn], 0, 0, 0);
            }
        }
#pragma unroll
        for (int tn = 0; tn < 4; ++tn) {
            const int j = 64 * w + 16 * tn + co;
            const float kp = (mask[(long)z * L_SEQ + j] > 0.f) ? 0.f : -INF_F;
#pragma unroll
            for (int rg = 0; rg < 2; ++rg)
#pragma unroll
                for (int r = 0; r < 4; ++r) {
                    const int rowL = 16 * rg + r0 + r;
                    const int cs = swz(rowL, j);
                    float val = acc[rg][tn][r] * 0.08838834764831845f +
                                (b2f(Sb[rowL][cs]) - mn) * inv + 1.f + kp;
                    Sb[rowL][cs] = f2b(val);
                }
        }
    }
    __syncthreads();

    // ---- phase 3: row softmax in LDS (2 rows/wave, conflict-free u16x2) -
    {
#pragma unroll
        for (int rr = 0; rr < 2; ++rr) {
            const int row = 2 * w + rr;
            const int sw = (row & 7) << 3;
            u16* prow = Sb[row];
            float f[16];
#pragma unroll
            for (int q = 0; q < 8; ++q) {
                ushort2 v = *reinterpret_cast<ushort2*>(
                    &prow[(lane * 2 + 128 * q) ^ sw]);
                f[2 * q + 0] = b2f(v.x);
                f[2 * q + 1] = b2f(v.y);
            }
            float m = f[0];
#pragma unroll
            for (int i = 1; i < 16; ++i) m = fmaxf(m, f[i]);
#pragma unroll
            for (int d2 = 1; d2 < 64; d2 <<= 1) m = fmaxf(m, __shfl_xor(m, d2));
            float s = 0.f;
#pragma unroll
            for (int i = 0; i < 16; ++i) {
                f[i] = __expf(f[i] - m);
                s += f[i];
            }
#pragma unroll
            for (int q = 0; q < 8; ++q) {
                ushort2 pv;
                pv.x = f2b(f[2 * q + 0]);
                pv.y = f2b(f[2 * q + 1]);
                *reinterpret_cast<ushort2*>(
                    &prow[(lane * 2 + 128 * q) ^ sw]) = pv;
            }
#pragma unroll
            for (int d2 = 1; d2 < 64; d2 <<= 1) s += __shfl_xor(s, d2);
            if (lane == 0) rsum[(long)z * L_SEQ + m0 + row] = 1.f / s;
        }
    }
    __syncthreads();

    // ---- phase 4: AV (A-frags from Sb, swizzled) ------------------------
    const int rg = w & 1, ch = w >> 1;      // row-group (16 rows), col-slice
    f32x4 av = 0.f;
    {
        const int arow = 16 * rg + co;
        const u16* Vz = vt + (long)z * 131072L + (long)(16 * ch + co) * 1024;
#pragma unroll 4
        for (int kk = 0; kk < 32; ++kk) {
            const int k0 = kk * 32 + q8;
            const s16x8 a = *reinterpret_cast<const s16x8*>(
                &Sb[arow][swz(arow, k0)]);
            const s16x8 b = *reinterpret_cast<const s16x8*>(Vz + k0);
            av = __builtin_amdgcn_mfma_f32_16x16x32_bf16(a, b, av, 0, 0, 0);
        }
    }
    __syncthreads();   // all Sb reads done; Sb dead, Tb/ps may alias

    u16 (*Tb)[136] = reinterpret_cast<u16 (*)[136]>(smem);   // 8704 B
    float* ps_s = reinterpret_cast<float*>(smem + 32768);    // [32][8]
    float* ps_q = reinterpret_cast<float*>(smem + 33792);    // [32][8]
    const int gj = 16 * ch + co;

    {
#pragma unroll
        for (int r = 0; r < 4; ++r) {
            const int rowL = 16 * rg + r0 + r;
            const float rsv = rsum[(long)z * L_SEQ + m0 + rowL];
            Tb[rowL][gj] = f2b(av[r] * rsv);
        }
    }
    __syncthreads();

    // ---- phase 5: wout(+h) -> ln1 -> ff1 -> ff2(+res) -> ln2 -> lin -----
    auto gemm32 = [&](const u16* __restrict__ Bw) -> f32x4 {
        f32x4 a4 = 0.f;
#pragma unroll
        for (int kk = 0; kk < 4; ++kk) {
            const int k0 = kk * 32 + q8;
            const s16x8 a = *reinterpret_cast<const s16x8*>(&Tb[16 * rg + co][k0]);
            const s16x8 b = *reinterpret_cast<const s16x8*>(
                Bw + (long)(16 * ch + co) * 128 + k0);
            a4 = __builtin_amdgcn_mfma_f32_16x16x32_bf16(a, b, a4, 0, 0, 0);
        }
        return a4;
    };

    float v2r[4];   // post-ln1 (ff2 residual)
    // WOUT + h residual + LN1
    {
        f32x4 vv = gemm32(woutb);
        const float bo = b_out[gj];
        const float* hz = h + ((long)z * L_SEQ + m0) * 128;
        float sr[4], qr[4];
#pragma unroll
        for (int r = 0; r < 4; ++r) {
            const int rowL = 16 * rg + r0 + r;
            float v1 = vv[r] + bo + hz[(long)rowL * 128 + gj];
            vv[r] = v1;
            sr[r] = v1;
            qr[r] = v1 * v1;
        }
#pragma unroll
        for (int m = 1; m < 16; m <<= 1)
#pragma unroll
            for (int r = 0; r < 4; ++r) {
                sr[r] += __shfl_xor(sr[r], m);
                qr[r] += __shfl_xor(qr[r], m);
            }
        if (co == 0) {
#pragma unroll
            for (int r = 0; r < 4; ++r) {
                const int rowL = 16 * rg + r0 + r;
                ps_s[rowL * 8 + ch] = sr[r];
                ps_q[rowL * 8 + ch] = qr[r];
            }
        }
        __syncthreads();   // ps visible; all Tb reads (wout) done
        const float g1 = ln1_g[gj], bb1 = ln1_b[gj];
#pragma unroll
        for (int r = 0; r < 4; ++r) {
            const int rowL = 16 * rg + r0 + r;
            float st = 0.f, qt = 0.f;
#pragma unroll
            for (int c = 0; c < 8; ++c) {
                st += ps_s[rowL * 8 + c];
                qt += ps_q[rowL * 8 + c];
            }
            const float mean = st * (1.f / 128.f);
            const float var = qt * (1.f / 128.f) - mean * mean;
            const float rstd = rsqrtf(var + 1e-5f);
            const float v = (vv[r] - mean) * rstd * g1 + bb1;
            v2r[r] = v;
            Tb[rowL][gj] = f2b(v);
        }
    }
    __syncthreads();

    // FF1 + relu
    {
        f32x4 f1 = gemm32(wff1b);
        __syncthreads();   // all Tb reads done
        const float bf = b_ff1[gj];
#pragma unroll
        for (int r = 0; r < 4; ++r)
            Tb[16 * rg + r0 + r][gj] = f2b(fmaxf(f1[r] + bf, 0.f));
    }
    __syncthreads();

    // FF2 + residual + LN2
    {
        f32x4 f2 = gemm32(wff2b);
        const float bf = b_ff2[gj];
        float sr[4], qr[4];
#pragma unroll
        for (int r = 0; r < 4; ++r) {
            float v3 = f2[r] + bf + v2r[r];
            f2[r] = v3;
            sr[r] = v3;
            qr[r] = v3 * v3;
        }
#pragma unroll
        for (int m = 1; m < 16; m <<= 1)
#pragma unroll
            for (int r = 0; r < 4; ++r) {
                sr[r] += __shfl_xor(sr[r], m);
                qr[r] += __shfl_xor(qr[r], m);
            }
        if (co == 0) {
#pragma unroll
            for (int r = 0; r < 4; ++r) {
                const int rowL = 16 * rg + r0 + r;
                ps_s[rowL * 8 + ch] = sr[r];
                ps_q[rowL * 8 + ch] = qr[r];
            }
        }
        __syncthreads();   // ps visible; all Tb reads (ff2) done
        const float g2 = ln2_g[gj], bb2 = ln2_b[gj];
#pragma unroll
        for (int r = 0; r < 4; ++r) {
            const int rowL = 16 * rg + r0 + r;
            float st = 0.f, qt = 0.f;
#pragma unroll
            for (int c = 0; c < 8; ++c) {
                st += ps_s[rowL * 8 + c];
                qt += ps_q[rowL * 8 + c];
            }
            const float mean = st * (1.f / 128.f);
            const float var = qt * (1.f / 128.f) - mean * mean;
            const float rstd = rsqrtf(var + 1e-5f);
            Tb[rowL][gj] = f2b((f2[r] - mean) * rstd * g2 + bb2);
        }
    }
    __syncthreads();

    // LIN (128 -> 16) * mask  (waves with ch==0 only)
    if (ch == 0) {
        f32x4 a1 = 0.f;
#pragma unroll
        for (int kk = 0; kk < 4; ++kk) {
            const int k0 = kk * 32 + q8;
            const s16x8 a = *reinterpret_cast<const s16x8*>(&Tb[16 * rg + co][k0]);
            const s16x8 b = *reinterpret_cast<const s16x8*>(
                wlinb + (long)co * 128 + k0);
            a1 = __builtin_amdgcn_mfma_f32_16x16x32_bf16(a, b, a1, 0, 0, 0);
        }
#pragma unroll
        for (int r = 0; r < 4; ++r) {
            const long grow = (long)z * L_SEQ + m0 + 16 * rg + r0 + r;
            out[grow * 16 + co] = a1[r] * mask[grow];
        }
    }
}

// ------------------------------- soft-DTW ----------------------------------
// base-2 scaled domain: n = d + mn - log2(1 + 2^(mn-md) + 2^(mn-mx))
__device__ __forceinline__ float softmin3(float d, float rl, float ru, float rul)
{
    float mn = fminf(rul, fminf(ru, rl));
    float md = __builtin_amdgcn_fmed3f(rul, ru, rl);
    float mx = fmaxf(rul, fmaxf(ru, rl));
    float s = 1.f + fexp2(mn - md) + fexp2(mn - mx);
    return d + mn - flog2(s);
}

#define DLOAD(i, P, OFFS)                                                \
    asm volatile("global_load_ushort %0, %1, off offset:" OFFS           \
                 : "=v"(dn[i]) : "v"(P))
#define RSTORE(i, P, OFFS)                                               \
    asm volatile("global_store_short_d16_hi %0, %1, off offset:" OFFS    \
                 :: "v"(P), "v"(nbuf[i]))

// Skewed [t&1023][row] layout, pointer-bumped addressing (R5/R8/R11).
template <bool EDGE, bool W0>
__device__ __forceinline__ void dtw_chunk1(
    const float* __restrict__ botp, float* __restrict__ botw,
    int lane, bool wstore, int rowbase, int row, int T0,
    float& cur, float& upc, float& upp,
    float (&dbuf)[8], float (&bb)[9], unsigned (&dn)[8],
    const u16*& ldp, u16*& stp)
{
    const bool lane0 = (lane == 0);
    for (int g = 0; g < 4; ++g) {
        const int tg = T0 + (g << 3);
        const int jg = tg - row;
        // ring-wrap corrections (wave-uniform; only at group boundaries)
        if (((tg + 8) & 1023) == 0) ldp -= 1048576;
        if (tg == 1024) stp -= 1048576;
        // issue next group's 8 D loads (steps tg+8 .. tg+15)
        {
            const u16* l2 = ldp + 2048;
            const u16* l4 = ldp + 4096;
            const u16* l6 = ldp + 6144;
            DLOAD(0, ldp, "0"); DLOAD(1, ldp, "2048");
            DLOAD(2, l2, "0");  DLOAD(3, l2, "2048");
            DLOAD(4, l4, "0");  DLOAD(5, l4, "2048");
            DLOAD(6, l6, "0");  DLOAD(7, l6, "2048");
        }
        float bn[9];
        if (!W0 && g < 3) {
            const int jn = tg + 7 - rowbase;
            if (EDGE) {
#pragma unroll
                for (int q = 0; q < 9; ++q) bn[q] = botp[(jn + q) & 1023];
            } else {
#pragma unroll
                for (int q = 0; q < 9; ++q) bn[q] = botp[jn + q];
            }
        }
        float nbuf[8];
#pragma unroll
        for (int s = 0; s < 8; ++s) {
            const int j = jg + s;
            float ru = lane0 ? (W0 ? INF_F : bb[s + 1]) : upc;
            float rul;
            if (EDGE) {
                if (W0) rul = lane0 ? ((j == 0) ? 0.f : INF_F) : upp;
                else    rul = (lane0 && (j < 1)) ? INF_F : upp;
            } else {
                rul = (W0 && lane0) ? INF_F : upp;
            }
            float n = softmin3(dbuf[s], cur, ru, rul);
            if (EDGE) n = ((unsigned)j < 1024u) ? n : INF_F;
            nbuf[s] = n;
            upp = ru;
            cur = n;
            upc = shup1(n);
        }
        // batched R stores (bf16-truncate via d16_hi)
        {
            u16* s2 = stp + 2048;
            u16* s4 = stp + 4096;
            u16* s6 = stp + 6144;
            if (EDGE) {
                if ((unsigned)(jg + 0) < 1024u) RSTORE(0, stp, "0");
                if ((unsigned)(jg + 1) < 1024u) RSTORE(1, stp, "2048");
                if ((unsigned)(jg + 2) < 1024u) RSTORE(2, s2, "0");
                if ((unsigned)(jg + 3) < 1024u) RSTORE(3, s2, "2048");
                if ((unsigned)(jg + 4) < 1024u) RSTORE(4, s4, "0");
                if ((unsigned)(jg + 5) < 1024u) RSTORE(5, s4, "2048");
                if ((unsigned)(jg + 6) < 1024u) RSTORE(6, s6, "0");
                if ((unsigned)(jg + 7) < 1024u) RSTORE(7, s6, "2048");
                asm volatile("s_waitcnt vmcnt(0)");
            } else {
                RSTORE(0, stp, "0"); RSTORE(1, stp, "2048");
                RSTORE(2, s2, "0");  RSTORE(3, s2, "2048");
                RSTORE(4, s4, "0");  RSTORE(5, s4, "2048");
                RSTORE(6, s6, "0");  RSTORE(7, s6, "2048");
                asm volatile("s_waitcnt vmcnt(8)");
            }
        }
        __builtin_amdgcn_sched_barrier(0);
        // batched bot handoff (lane 63 only, consumed next epoch)
        if (lane == 63 && wstore) {
            if (EDGE) {
#pragma unroll
                for (int s = 0; s < 8; ++s) {
                    int j = jg + s;
                    if ((unsigned)j < 1024u) botw[j] = nbuf[s];
                }
            } else {
#pragma unroll
                for (int s = 0; s < 8; ++s) botw[jg + s] = nbuf[s];
            }
        }
#pragma unroll
        for (int s = 0; s < 8; ++s) dbuf[s] = __uint_as_float(dn[s] << 16);
        if (!W0 && g < 3) {
#pragma unroll
            for (int q = 0; q < 9; ++q) bb[q] = bn[q];
        }
        ldp += 8192;
        stp += 8192;
    }
}

// dtw (blocks 0..31: 1 per sample, 16 waves) + QKV backfill (blocks 32..799)
__global__ __launch_bounds__(1024, 4) void dtw_qkv_k(
    const u16* __restrict__ Dm, u16* __restrict__ Rm,
    const float* __restrict__ h, const float* __restrict__ w_in,
    const float* __restrict__ b_in, u16* __restrict__ qb, u16* __restrict__ vt)
{
    // unioned LDS: QKV As(16640)+Bs(16640)|Tt(33280)  |  dtw bot 15x1024 f32
    __shared__ __align__(16) char smem[61440];

    if (blockIdx.x >= 32) {
        // ---- QKV backfill: four 64x64 tiles per 1024-thread block ----
        float (*As)[16][65] = reinterpret_cast<float (*)[16][65]>(smem);
        float (*Bs)[16][65] = reinterpret_cast<float (*)[16][65]>(smem + 16640);
        const int quarter = threadIdx.x >> 8;
        const int tid = threadIdx.x & 255;
        const int t = ((blockIdx.x - 32) << 2) + quarter;   // 0..3071
        const int m0 = (t & 511) << 6;
        const int n0 = (t >> 9) << 6;                       // block-uniform
        int tx = tid & 15, ty = tid >> 4;
        float acc[4][4] = {};
        int am = tid >> 2;
        int ak = (tid & 3) << 2;
        for (int kk = 0; kk < 128; kk += 16) {
            {
                const float4 av = *reinterpret_cast<const float4*>(
                    h + (long)(m0 + am) * 128 + kk + ak);
                As[quarter][ak + 0][am] = av.x;
                As[quarter][ak + 1][am] = av.y;
                As[quarter][ak + 2][am] = av.z;
                As[quarter][ak + 3][am] = av.w;
            }
            {
                const float4 bv = *reinterpret_cast<const float4*>(
                    w_in + (long)(n0 + am) * 128 + kk + ak);
                Bs[quarter][ak + 0][am] = bv.x;
                Bs[quarter][ak + 1][am] = bv.y;
                Bs[quarter][ak + 2][am] = bv.z;
                Bs[quarter][ak + 3][am] = bv.w;
            }
            __syncthreads();
#pragma unroll
            for (int kc = 0; kc < 16; ++kc) {
                float a0 = As[quarter][kc][ty * 4 + 0], a1 = As[quarter][kc][ty * 4 + 1];
                float a2 = As[quarter][kc][ty * 4 + 2], a3 = As[quarter][kc][ty * 4 + 3];
                float b0 = Bs[quarter][kc][tx * 4 + 0], b1 = Bs[quarter][kc][tx * 4 + 1];
                float b2 = Bs[quarter][kc][tx * 4 + 2], b3 = Bs[quarter][kc][tx * 4 + 3];
                acc[0][0] += a0 * b0; acc[0][1] += a0 * b1; acc[0][2] += a0 * b2; acc[0][3] += a0 * b3;
                acc[1][0] += a1 * b0; acc[1][1] += a1 * b1; acc[1][2] += a1 * b2; acc[1][3] += a1 * b3;
                acc[2][0] += a2 * b0; acc[2][1] += a2 * b1; acc[2][2] += a2 * b2; acc[2][3] += a2 * b3;
                acc[3][0] += a3 * b0; acc[3][1] += a3 * b1; acc[3][2] += a3 * b2; acc[3][3] += a3 * b3;
            }
            __syncthreads();
        }
        if (n0 >= 256) {
            // v-tile: write TRANSPOSED into vt [d,1024] via LDS
            u16 (*Tt)[64][65] = reinterpret_cast<u16 (*)[64][65]>(smem);
#pragma unroll
            for (int i = 0; i < 4; ++i)
#pragma unroll
                for (int j = 0; j < 4; ++j)
                    Tt[quarter][tx * 4 + j][ty * 4 + i] =
                        f2b(acc[i][j] + b_in[n0 + tx * 4 + j]);
            __syncthreads();
            const int z = m0 >> 10;
            const int lbase = m0 & 1023;
            const int dbase = n0 - 256;
            u16* dst = vt + (long)z * 131072L;
#pragma unroll
            for (int i = 0; i < 16; ++i) {
                int idx = tid + 256 * i;
                int dj = idx >> 6, li = idx & 63;
                dst[(long)(dbase + dj) * 1024 + lbase + li] = Tt[quarter][dj][li];
            }
            return;
        }
        u16* Cu = qb + ((long)(n0 >> 7)) * 4194304L;
        int cb = (n0 & 127) + tx * 4;
#pragma unroll
        for (int i = 0; i < 4; ++i) {
            int gi = m0 + ty * 4 + i;
            ushort4 sv;
            u16* svp = &sv.x;
#pragma unroll
            for (int j = 0; j < 4; ++j)
                svp[j] = f2b(acc[i][j] + b_in[n0 + tx * 4 + j]);
            *reinterpret_cast<ushort4*>(Cu + (long)gi * 128 + cb) = sv;
        }
        return;
    }

    // ------------------------------- dtw ---------------------------------
    float (*bot)[1024] = reinterpret_cast<float (*)[1024]>(smem);
    const int z = blockIdx.x;
    const u16* Dz = Dm + (long)z * 1048576L;
    u16* Rz = Rm + (long)z * 1048576L;
    const int tid = threadIdx.x;
    const int W = tid >> 6;           // 0..15, 64 rows each
    const int lane = tid & 63;
    const int rowbase = 64 * W;
    const int row = rowbase + lane;
    const bool wstore = (W < 15);

    float* botw = (W < 15) ? bot[W] : bot[0];
    const float* botp = (W > 0) ? bot[W - 1] : bot[0];

    float cur = INF_F, upc = INF_F, upp = INF_F;
    float dbuf[8];
    float bb[9];
    unsigned dn[8];
    const u16* ldp = Dz;
    u16* stp = Rz;
#pragma unroll
    for (int q = 0; q < 9; ++q) bb[q] = 0.f;
#pragma unroll
    for (int q = 0; q < 8; ++q) dn[q] = 0;

    const int fc = 2 * W;
    for (int e = 0; e < 79; ++e) {
        const int c = e - W;
        const int o = c - fc;
        if (o >= 0 && o <= 33) {
            const int T0 = c << 5;
            if (o == 0) {   // prime pointers + D queue (first chunk only)
                ldp = Dz + (long)((((T0 + 8) & 1023) << 10) + row);
                stp = Rz + (long)(((T0 & 1023) << 10) + row);
#pragma unroll
                for (int s = 0; s < 8; ++s)
                    dbuf[s] = b2f(Dz[((((T0 + s) & 1023) << 10) + row)]);
            }
            if (W > 0) {    // bot columns for the chunk's first group
                const int jb = T0 - rowbase - 1;
#pragma unroll
                for (int q = 0; q < 9; ++q) bb[q] = botp[(jb + q) & 1023];
            }
            const bool edge = (o < 2 || o >= 32);
            if (W == 0) {
                if (edge)
                    dtw_chunk1<true, true>(botp, botw, lane, wstore, rowbase,
                                           row, T0, cur, upc, upp,
                                           dbuf, bb, dn, ldp, stp);
                else
                    dtw_chunk1<false, true>(botp, botw, lane, wstore, rowbase,
                                            row, T0, cur, upc, upp,
                                            dbuf, bb, dn, ldp, stp);
            } else {
                if (edge)
                    dtw_chunk1<true, false>(botp, botw, lane, wstore, rowbase,
                                            row, T0, cur, upc, upp,
                                            dbuf, bb, dn, ldp, stp);
                else
                    dtw_chunk1<false, false>(botp, botw, lane, wstore, rowbase,
                                             row, T0, cur, upc, upp,
                                             dbuf, bb, dn, ldp, stp);
            }
        }
        __syncthreads();
    }
}

// --------- min/max partials over Rmat (8 blocks/sample, full-GPU BW) -------
__global__ __launch_bounds__(1024) void mm_k(const u16* __restrict__ Rm,
                                             float* __restrict__ mnmx8)
{
    const int z = blockIdx.x >> 3, ch = blockIdx.x & 7;
    const uint4* p = reinterpret_cast<const uint4*>(Rm + (long)z * 1048576L) +
                     (long)ch * 16384;
    const int tid = threadIdx.x;
    float mn = INF_F, mx = -INF_F;
#pragma unroll 4
    for (int it = 0; it < 16; ++it) {
        uint4 v = p[it * 1024 + tid];
        unsigned wv[4] = {v.x, v.y, v.z, v.w};
#pragma unroll
        for (int q = 0; q < 4; ++q) {
            float lo = __uint_as_float(wv[q] << 16);
            float hi = __uint_as_float(wv[q] & 0xFFFF0000u);
            mn = fminf(mn, fminf(lo, hi));
            mx = fmaxf(mx, fmaxf(lo, hi));
        }
    }
    __shared__ float rmn[1024];
    __shared__ float rmx[1024];
    rmn[tid] = mn;
    rmx[tid] = mx;
    __syncthreads();
    for (int s2 = 512; s2 > 0; s2 >>= 1) {
        if (tid < s2) {
            rmn[tid] = fminf(rmn[tid], rmn[tid + s2]);
            rmx[tid] = fmaxf(rmx[tid], rmx[tid + s2]);
        }
        __syncthreads();
    }
    if (tid == 0) {
        mnmx8[blockIdx.x * 2 + 0] = rmn[0];
        mnmx8[blockIdx.x * 2 + 1] = rmx[0];
    }
}

// -------------------------------- lengths ----------------------------------
__global__ __launch_bounds__(256) void len_k(const float* __restrict__ mask,
                                             float* __restrict__ out)
{
    int b = blockIdx.x;
    int t = threadIdx.x;
    const float4 v = reinterpret_cast<const float4*>(mask + b * L_SEQ)[t];
    __shared__ float red[256];
    red[t] = v.x + v.y + v.z + v.w;
    __syncthreads();
    for (int s = 128; s > 0; s >>= 1) {
        if (t < s) red[t] += red[t + s];
        __syncthreads();
    }
    if (t == 0) out[b] = red[0];
}

// ------------------------------- launcher ----------------------------------
extern "C" void kernel_launch(void* const* d_in, const int* in_sizes, int n_in,
                              void* d_out, int out_size, void* d_ws, size_t ws_size,
                              hipStream_t stream)
{
    const float* x      = (const float*)d_in[0];
    const float* mask   = (const float*)d_in[1];
    const float* conv_w = (const float*)d_in[2];
    const float* conv_b = (const float*)d_in[3];
    const float* w_in   = (const float*)d_in[4];
    const float* b_in   = (const float*)d_in[5];
    const float* w_out  = (const float*)d_in[6];
    const float* b_out  = (const float*)d_in[7];
    const float* w_ff1  = (const float*)d_in[8];
    const float* b_ff1  = (const float*)d_in[9];
    const float* w_ff2  = (const float*)d_in[10];
    const float* b_ff2  = (const float*)d_in[11];
    const float* ln1_g  = (const float*)d_in[12];
    const float* ln1_b  = (const float*)d_in[13];
    const float* ln2_g  = (const float*)d_in[14];
    const float* ln2_b  = (const float*)d_in[15];
    const float* w_lin  = (const float*)d_in[16];
    float* out = (float*)d_out;

    float* ws    = (float*)d_ws;
    float* h     = ws;
    u16*   qb    = (u16*)(ws + 4194304L);
    u16*   kb    = qb + 4194304L;
    u16*   vt    = qb + 12582912L;
    u16*   hbf   = (u16*)(ws + 25165824L);
    float* mnmx8 = ws + 27297792L;            // 512 floats of partials
    float* norms = ws + 29360128L;
    u16*   woutb = (u16*)norms;               // weights after D2 consumed norms
    float* rsum  = ws + 29425664L;
    u16*   Dmat  = (u16*)(ws + 29458496L);    // D (dtw input; dead after dtw)
    u16*   Rmat  = (u16*)(ws + 46235712L);    // R (dtw output, mm/attn input)

    conv_k<<<dim3(32, 128), 128, 0, stream>>>(x, conv_w, conv_b, mask, h, hbf, norms);
    mgemm_k<<<dim3(16, 16, 32), 256, 0, stream>>>(hbf, hbf, Dmat, norms);
    wcvt_k<<<200, 256, 0, stream>>>(w_out, w_ff1, w_ff2, w_lin, woutb);
    // dtw (32 blocks, 1/sample, 16 waves) + qkv backfill (768 blocks x 4 tiles)
    dtw_qkv_k<<<800, 1024, 0, stream>>>(Dmat, Rmat, h, w_in, b_in, qb, vt);
    mm_k<<<256, 1024, 0, stream>>>(Rmat, mnmx8);
    // fused attention: R-stage + QK + softmax + AV + transformer tail
    attn_k<<<dim3(32, 32), 1024, 0, stream>>>(
        qb, kb, vt, Rmat, mnmx8, mask, rsum, h, woutb, b_out,
        ln1_g, ln1_b, b_ff1, b_ff2, ln2_g, ln2_b, out);
    len_k<<<32, 256, 0, stream>>>(mask, out + 32768L * 16);
}